// Round 4
// baseline (156.254 us; speedup 1.0000x reference)
//
#include <hip/hip_runtime.h>
#include <stdint.h>

typedef unsigned short u16;
typedef unsigned long long u64;
typedef __attribute__((ext_vector_type(8))) short short8;
typedef __attribute__((ext_vector_type(4))) float f32x4;

#define MFMA16 __builtin_amdgcn_mfma_f32_16x16x32_bf16

#define B_ 1024
#define N_ 64
#define H_ 256
#define MTOT (B_ * N_)   // 65536

__device__ __forceinline__ u16 f2bf(float f) {
  union { float f; uint32_t u; } v; v.f = f;
  uint32_t r = v.u + 0x7FFFu + ((v.u >> 16) & 1u);
  return (u16)(r >> 16);
}

union U8 { short8 v; u16 u[8]; };
union U4 { u64 v; u16 u[4]; };

__device__ __forceinline__ void cp16(const void* g, void* l) {
  __builtin_amdgcn_global_load_lds(
      (const __attribute__((address_space(1))) void*)g,
      (__attribute__((address_space(3))) void*)l, 16, 0, 0);
}

// ---------------------------------------------------------------------------
// wconv: fp32 -> bf16 weights
// ---------------------------------------------------------------------------
__global__ __launch_bounds__(256) void wconv(
    const float* __restrict__ W1, const float* __restrict__ W2,
    const float* __restrict__ Wq, const float* __restrict__ Wk,
    const float* __restrict__ Wv,
    u16* o1, u16* o2, u16* oq, u16* ok, u16* ov) {
  int off8 = blockIdx.x * 256 + threadIdx.x;
  const float* src; u16* dst;
  if      (off8 <  4096) { src = W1; dst = o1; }
  else if (off8 < 12288) { src = W2; dst = o2; off8 -= 4096; }
  else if (off8 < 20480) { src = Wq; dst = oq; off8 -= 12288; }
  else if (off8 < 28672) { src = Wk; dst = ok; off8 -= 20480; }
  else                   { src = Wv; dst = ov; off8 -= 28672; }
  const int e = off8 * 8;
  f32x4 a = *(const f32x4*)(src + e);
  f32x4 b = *(const f32x4*)(src + e + 4);
  U8 pk;
#pragma unroll
  for (int j = 0; j < 4; j++) { pk.u[j] = f2bf(a[j]); pk.u[4 + j] = f2bf(b[j]); }
  *(short8*)(dst + e) = pk.v;
}

// ---------------------------------------------------------------------------
// prep1: M1 = Wc @ Wo (fp32), bv = bc + Wc @ bo
// ---------------------------------------------------------------------------
__global__ __launch_bounds__(256) void prep1(
    const float* __restrict__ Wc, const float* __restrict__ Wo,
    const float* __restrict__ bo, const float* __restrict__ bc,
    float* __restrict__ M1, float* __restrict__ bv) {
  const int j = blockIdx.x, d = threadIdx.x;
  __shared__ float wcr[256];
  __shared__ float red[4];
  wcr[d] = Wc[j * 256 + d];
  __syncthreads();
  float acc = 0.f;
  for (int i = 0; i < 256; i++) acc += wcr[i] * Wo[i * 256 + d];
  M1[j * 256 + d] = acc;
  float p = wcr[d] * bo[d];
  for (int off = 32; off >= 1; off >>= 1) p += __shfl_xor(p, off);
  if ((d & 63) == 0) red[d >> 6] = p;
  __syncthreads();
  if (d == 0) bv[j] = bc[j] + red[0] + red[1] + red[2] + red[3];
}

// prep2: Wz = W3 @ M1 (bf16), bz = W3 @ bv
__global__ __launch_bounds__(256) void prep2(
    const float* __restrict__ W3, const float* __restrict__ M1,
    const float* __restrict__ bv, u16* __restrict__ Wz,
    float* __restrict__ bz) {
  const int a = blockIdx.x, d = threadIdx.x;
  __shared__ float w3r[256];
  __shared__ float red[4];
  w3r[d] = W3[a * 256 + d];
  __syncthreads();
  float acc = 0.f;
  for (int j = 0; j < 256; j++) acc += w3r[j] * M1[j * 256 + d];
  Wz[a * 256 + d] = f2bf(acc);
  float p = w3r[d] * bv[d];
  for (int off = 32; off >= 1; off >>= 1) p += __shfl_xor(p, off);
  if ((d & 63) == 0) red[d >> 6] = p;
  __syncthreads();
  if (d == 0) bz[a] = red[0] + red[1] + red[2] + red[3];
}

// ---------------------------------------------------------------------------
// gemm1: x1[M,256] = relu(obs[M,128] @ W1[256,128]^T + b1) -> bf16 std layout.
// 128x256 tile, BK=64, 4 waves, 4x8 frags. (fp32 A, converted in staging)
// ---------------------------------------------------------------------------
__global__ __launch_bounds__(256, 2) void gemm1(
    const float* __restrict__ Af, const u16* __restrict__ Wb,
    const float* __restrict__ bias, u16* __restrict__ C) {
  __shared__ char smem[49152];
  u16* As = (u16*)smem;            // 128x64 bf16, linear
  u16* Bs = (u16*)(smem + 16384);  // 256x64 bf16, linear
  const int tid = threadIdx.x;
  const int lane = tid & 63, wid = tid >> 6;
  const int wr = wid >> 1, wc = wid & 1;
  const int ro = lane & 15, hi = lane >> 4;
  const int m0 = blockIdx.x * 128;
  const int K = 128;

  f32x4 acc[4][8];
#pragma unroll
  for (int m = 0; m < 4; m++)
#pragma unroll
    for (int n = 0; n < 8; n++) acc[m][n] = (f32x4){0.f, 0.f, 0.f, 0.f};

  for (int k0 = 0; k0 < K; k0 += 64) {
#pragma unroll
    for (int it = 0; it < 4; it++) {
      const int e = (tid + it * 256) * 8;
      const int r = e >> 6, c = e & 63;
      const float* s = Af + (size_t)(m0 + r) * K + k0 + c;
      f32x4 a = *(const f32x4*)s, b = *(const f32x4*)(s + 4);
      U8 pk;
#pragma unroll
      for (int j = 0; j < 4; j++) { pk.u[j] = f2bf(a[j]); pk.u[4 + j] = f2bf(b[j]); }
      *(short8*)&As[r * 64 + c] = pk.v;
    }
#pragma unroll
    for (int i = 0; i < 8; i++) {
      const int boff = i * 4096 + wid * 1024;
      const int loff = boff + lane * 16;
      const int r = loff >> 7, cb = loff & 127;
      cp16(Wb + (size_t)r * K + k0 + (cb >> 1), Bs + (boff >> 1));
    }
    __syncthreads();
#pragma unroll
    for (int kk = 0; kk < 64; kk += 32) {
      short8 af[4], bfr[8];
#pragma unroll
      for (int m = 0; m < 4; m++)
        af[m] = *(const short8*)&As[(wr * 64 + m * 16 + ro) * 64 + kk + hi * 8];
#pragma unroll
      for (int n = 0; n < 8; n++)
        bfr[n] = *(const short8*)&Bs[(wc * 128 + n * 16 + ro) * 64 + kk + hi * 8];
#pragma unroll
      for (int m = 0; m < 4; m++)
#pragma unroll
        for (int n = 0; n < 8; n++)
          acc[m][n] = MFMA16(af[m], bfr[n], acc[m][n], 0, 0, 0);
    }
    __syncthreads();
  }

  u16 (*Cs)[264] = (u16(*)[264])smem;
#pragma unroll
  for (int half = 0; half < 2; half++) {
    if (wr == half) {
#pragma unroll
      for (int n = 0; n < 8; n++) {
        const int col = wc * 128 + n * 16 + ro;
        const float bb = bias[col];
#pragma unroll
        for (int m = 0; m < 4; m++) {
#pragma unroll
          for (int j = 0; j < 4; j++) {
            float val = fmaxf(acc[m][n][j] + bb, 0.f);
            Cs[m * 16 + hi * 4 + j][col] = f2bf(val);
          }
        }
      }
    }
    __syncthreads();
    for (int i = tid; i < 64 * 32; i += 256) {
      const int r = i >> 5, c = (i & 31) << 3;
      *(short8*)(C + (size_t)(m0 + half * 64 + r) * 256 + c) = *(short8*)&Cs[r][c];
    }
    __syncthreads();
  }
}

// ---------------------------------------------------------------------------
// qkv_fused: per 64-row tile (= one b): x2 = relu(x1@W2^T+b2) kept in LDS;
// Q = x2@Wq^T+bq (std), K = x2@Wk^T+bk (std), V^T = (x2@Wv^T+bv)^T (direct).
// 4 waves; wave w owns output cols w*64..w*64+63. Weight B-frags read
// directly from global (L2-resident, no duplication across waves).
// X region XOR-swizzled (row&7)<<4; staged with pre-swizzled global src.
// ---------------------------------------------------------------------------
__global__ __launch_bounds__(256, 2) void qkv_fused(
    const u16* __restrict__ x1g, const u16* __restrict__ W2b,
    const float* __restrict__ b2, const u16* __restrict__ Wqb,
    const float* __restrict__ bqv, const u16* __restrict__ Wkb,
    const float* __restrict__ bkv, const u16* __restrict__ Wvb,
    const float* __restrict__ bvv,
    u16* __restrict__ Qg, u16* __restrict__ Kg, u16* __restrict__ Vt) {
  __shared__ char X[32768];        // x1 then x2: [64][256] bf16, swizzled
  __shared__ u16 E[64][264];       // std-layout epilogue buffer
  const int tid = threadIdx.x, lane = tid & 63, w = tid >> 6;
  const int ro = lane & 15, hi = lane >> 4;
  const size_t m0 = (size_t)blockIdx.x * 64;
  const int cbase = w * 64;

  // stage x1: linear LDS dest, pre-swizzled global source (rule 21 / m173)
#pragma unroll
  for (int it = 0; it < 8; ++it) {
    const int boff = it * 4096 + w * 1024;
    const int t = boff + lane * 16;
    const int row = t >> 9;
    const int cb = (t & 511) ^ ((row & 7) << 4);
    cp16(x1g + (m0 + row) * 256 + (cb >> 1), X + boff);
  }
  __syncthreads();

  f32x4 acc[4][4];
  // compute: acc = X[64x256] @ Wb[cbase..cbase+63][256]^T
  auto run = [&](const u16* __restrict__ Wb) {
#pragma unroll
    for (int m = 0; m < 4; m++)
#pragma unroll
      for (int n = 0; n < 4; n++) acc[m][n] = (f32x4){0.f, 0.f, 0.f, 0.f};
#pragma unroll
    for (int kk = 0; kk < 256; kk += 32) {
      short8 af[4], bf_[4];
#pragma unroll
      for (int m = 0; m < 4; m++) {
        const int row = m * 16 + ro;
        af[m] = *(const short8*)(X + ((row * 512 + (kk + hi * 8) * 2) ^ ((row & 7) << 4)));
      }
#pragma unroll
      for (int n = 0; n < 4; n++)
        bf_[n] = *(const short8*)(Wb + (size_t)(cbase + n * 16 + ro) * 256 + kk + hi * 8);
#pragma unroll
      for (int m = 0; m < 4; m++)
#pragma unroll
        for (int n = 0; n < 4; n++)
          acc[m][n] = MFMA16(af[m], bf_[n], acc[m][n], 0, 0, 0);
    }
  };

  // ---- phase 1: x2 = relu(x1@W2^T + b2), overwrite X ----
  run(W2b);
  __syncthreads();   // all x1 reads done
  {
    float bias[4];
#pragma unroll
    for (int n = 0; n < 4; n++) bias[n] = b2[cbase + n * 16 + ro];
#pragma unroll
    for (int m = 0; m < 4; m++)
#pragma unroll
      for (int n = 0; n < 4; n++) {
        const int col = cbase + n * 16 + ro;
#pragma unroll
        for (int j = 0; j < 4; j++) {
          const int row = m * 16 + hi * 4 + j;
          const float v = fmaxf(acc[m][n][j] + bias[n], 0.f);
          *(u16*)(X + ((row * 512 + col * 2) ^ ((row & 7) << 4))) = f2bf(v);
        }
      }
  }
  __syncthreads();

  // ---- phase 2: Q ----
  run(Wqb);
  {
    float bias[4];
#pragma unroll
    for (int n = 0; n < 4; n++) bias[n] = bqv[cbase + n * 16 + ro];
#pragma unroll
    for (int m = 0; m < 4; m++)
#pragma unroll
      for (int n = 0; n < 4; n++)
#pragma unroll
        for (int j = 0; j < 4; j++)
          E[m * 16 + hi * 4 + j][cbase + n * 16 + ro] = f2bf(acc[m][n][j] + bias[n]);
  }
  __syncthreads();
  // store Q from E (overlaps with K compute)
  for (int i = tid; i < 2048; i += 256) {
    const int r = i >> 5, c = (i & 31) << 3;
    *(short8*)(Qg + (m0 + r) * 256 + c) = *(short8*)&E[r][c];
  }

  // ---- phase 3: K ----
  run(Wkb);
  __syncthreads();   // E reads (Q stores) done
  {
    float bias[4];
#pragma unroll
    for (int n = 0; n < 4; n++) bias[n] = bkv[cbase + n * 16 + ro];
#pragma unroll
    for (int m = 0; m < 4; m++)
#pragma unroll
      for (int n = 0; n < 4; n++)
#pragma unroll
        for (int j = 0; j < 4; j++)
          E[m * 16 + hi * 4 + j][cbase + n * 16 + ro] = f2bf(acc[m][n][j] + bias[n]);
  }
  __syncthreads();
  for (int i = tid; i < 2048; i += 256) {
    const int r = i >> 5, c = (i & 31) << 3;
    *(short8*)(Kg + (m0 + r) * 256 + c) = *(short8*)&E[r][c];
  }

  // ---- phase 4: V, direct transposed store Vt[b][d][k] ----
  run(Wvb);
  {
    float bias[4];
#pragma unroll
    for (int n = 0; n < 4; n++) bias[n] = bvv[cbase + n * 16 + ro];
#pragma unroll
    for (int n = 0; n < 4; n++) {
      const int d = cbase + n * 16 + ro;
#pragma unroll
      for (int m = 0; m < 4; m++) {
        U4 pk;
#pragma unroll
        for (int j = 0; j < 4; j++) pk.u[j] = f2bf(acc[m][n][j] + bias[n]);
        *(u64*)(Vt + (size_t)blockIdx.x * 16384 + (size_t)d * 64 + m * 16 + hi * 4) = pk.v;
      }
    }
  }
}

// ---------------------------------------------------------------------------
// attn_fused: per b. Q/K/V frags direct from global (V pre-transposed).
// ---------------------------------------------------------------------------
__global__ __launch_bounds__(256, 2) void attn_fused(
    const u16* __restrict__ Qg, const u16* __restrict__ Kg,
    const u16* __restrict__ Vt, const float* __restrict__ adj,
    const u16* __restrict__ Wz, const float* __restrict__ bz,
    const float* __restrict__ b3, float* __restrict__ out) {
  __shared__ u16 Ps[4][64][72];
  __shared__ float Zs[64][16];
  __shared__ u64 adjm[64];
  __shared__ u16 chunk[64][4];

  const int b = blockIdx.x, tid = threadIdx.x;
  const int lane = tid & 63, w = tid >> 6;
  const int ro = lane & 15, hi = lane >> 4;
  const int hc = w * 64;
  const size_t base = (size_t)b * 64 * 256;

  short8 kb[4][2];
#pragma unroll
  for (int n = 0; n < 4; n++)
#pragma unroll
    for (int ks = 0; ks < 2; ks++)
      kb[n][ks] = *(const short8*)(Kg + base + (size_t)(n * 16 + ro) * 256 + hc + ks * 32 + hi * 8);

  {
    const int q = tid >> 2, qa = tid & 3;
    const float* ar = adj + ((size_t)b * 64 + q) * 64 + qa * 16;
    f32x4 a0 = *(const f32x4*)(ar);
    f32x4 a1 = *(const f32x4*)(ar + 4);
    f32x4 a2 = *(const f32x4*)(ar + 8);
    f32x4 a3 = *(const f32x4*)(ar + 12);
    unsigned m16 = 0;
#pragma unroll
    for (int i = 0; i < 4; i++) {
      m16 |= (unsigned)(a0[i] != 0.f) << i;
      m16 |= (unsigned)(a1[i] != 0.f) << (4 + i);
      m16 |= (unsigned)(a2[i] != 0.f) << (8 + i);
      m16 |= (unsigned)(a3[i] != 0.f) << (12 + i);
    }
    chunk[q][qa] = (u16)m16;
  }

  f32x4 s[4][4];
#pragma unroll
  for (int m = 0; m < 4; m++) {
    short8 af[2];
#pragma unroll
    for (int ks = 0; ks < 2; ks++)
      af[ks] = *(const short8*)(Qg + base + (size_t)(m * 16 + ro) * 256 + hc + ks * 32 + hi * 8);
#pragma unroll
    for (int n = 0; n < 4; n++) s[m][n] = (f32x4){0.f, 0.f, 0.f, 0.f};
#pragma unroll
    for (int ks = 0; ks < 2; ks++)
#pragma unroll
      for (int n = 0; n < 4; n++)
        s[m][n] = MFMA16(af[ks], kb[n][ks], s[m][n], 0, 0, 0);
  }

  short8 vb[4][2];
#pragma unroll
  for (int n = 0; n < 4; n++)
#pragma unroll
    for (int ks = 0; ks < 2; ks++)
      vb[n][ks] = *(const short8*)(Vt + (size_t)b * 16384 + (size_t)(hc + n * 16 + ro) * 64 + ks * 32 + hi * 8);

  __syncthreads();
  if (tid < 64)
    adjm[tid] = (u64)chunk[tid][0] | ((u64)chunk[tid][1] << 16) |
                ((u64)chunk[tid][2] << 32) | ((u64)chunk[tid][3] << 48);
  __syncthreads();

#pragma unroll
  for (int m = 0; m < 4; m++) {
#pragma unroll
    for (int j = 0; j < 4; j++) {
      const int q = m * 16 + hi * 4 + j;
      const u64 msk = adjm[q];
      float sv[4], ev[4];
      float mx = -3.0e38f;
#pragma unroll
      for (int n = 0; n < 4; n++) {
        const bool on = (msk >> (n * 16 + ro)) & 1ull;
        sv[n] = on ? s[m][n][j] * 0.125f : -3.0e38f;
        mx = fmaxf(mx, sv[n]);
      }
      mx = fmaxf(mx, __shfl_xor(mx, 1));
      mx = fmaxf(mx, __shfl_xor(mx, 2));
      mx = fmaxf(mx, __shfl_xor(mx, 4));
      mx = fmaxf(mx, __shfl_xor(mx, 8));
      float sum = 0.f;
#pragma unroll
      for (int n = 0; n < 4; n++) {
        ev[n] = (sv[n] > -1.0e37f) ? __expf(sv[n] - mx) : 0.f;
        sum += ev[n];
      }
      sum += __shfl_xor(sum, 1);
      sum += __shfl_xor(sum, 2);
      sum += __shfl_xor(sum, 4);
      sum += __shfl_xor(sum, 8);
      const float inv = 1.0f / sum;
#pragma unroll
      for (int n = 0; n < 4; n++)
        Ps[w][q][n * 16 + ro] = f2bf(ev[n] * inv);
    }
  }

  f32x4 o[4][4];
#pragma unroll
  for (int m = 0; m < 4; m++) {
    short8 pa[2];
    pa[0] = *(const short8*)&Ps[w][m * 16 + ro][hi * 8];
    pa[1] = *(const short8*)&Ps[w][m * 16 + ro][32 + hi * 8];
#pragma unroll
    for (int n = 0; n < 4; n++) o[m][n] = (f32x4){0.f, 0.f, 0.f, 0.f};
#pragma unroll
    for (int ks = 0; ks < 2; ks++)
#pragma unroll
      for (int n = 0; n < 4; n++)
        o[m][n] = MFMA16(pa[ks], vb[n][ks], o[m][n], 0, 0, 0);
  }
#pragma unroll
  for (int m = 0; m < 4; m++)
#pragma unroll
    for (int n = 0; n < 4; n++)
#pragma unroll
      for (int j = 0; j < 4; j++)
        Ps[w][m * 16 + hi * 4 + j][n * 16 + ro] = f2bf(o[m][n][j]);
  __syncthreads();

  {
    f32x4 za = (f32x4){0.f, 0.f, 0.f, 0.f};
#pragma unroll
    for (int head = 0; head < 4; head++) {
#pragma unroll
      for (int ks = 0; ks < 2; ks++) {
        short8 oa = *(const short8*)&Ps[head][w * 16 + ro][ks * 32 + hi * 8];
        short8 wzb = *(const short8*)(Wz + ro * 256 + head * 64 + ks * 32 + hi * 8);
        za = MFMA16(oa, wzb, za, 0, 0, 0);
      }
    }
#pragma unroll
    for (int j = 0; j < 4; j++)
      Zs[w * 16 + hi * 4 + j][ro] = za[j];
  }
  __syncthreads();

  {
    const int n = tid >> 2, a4 = (tid & 3) << 2;
    const u64 msk = adjm[n];
    const float deg = (float)__popcll(msk);
    float a0 = 0.f, a1 = 0.f, a2 = 0.f, a3 = 0.f;
#pragma unroll 8
    for (int m = 0; m < 64; m++) {
      const float wv = (float)((msk >> m) & 1ull);
      f32x4 z = *(const f32x4*)&Zs[m][a4];
      a0 += wv * z[0]; a1 += wv * z[1]; a2 += wv * z[2]; a3 += wv * z[3];
    }
    f32x4 r;
    r[0] = a0 + b3[a4 + 0] + deg * bz[a4 + 0];
    r[1] = a1 + b3[a4 + 1] + deg * bz[a4 + 1];
    r[2] = a2 + b3[a4 + 2] + deg * bz[a4 + 2];
    r[3] = a3 + b3[a4 + 3] + deg * bz[a4 + 3];
    *(f32x4*)(out + ((size_t)b * 64 + n) * 16 + a4) = r;
  }
}

// ---------------------------------------------------------------------------
extern "C" void kernel_launch(void* const* d_in, const int* in_sizes, int n_in,
                              void* d_out, int out_size, void* d_ws, size_t ws_size,
                              hipStream_t stream) {
  const float* obs = (const float*)d_in[0];
  const float* adj = (const float*)d_in[1];
  const float* W1  = (const float*)d_in[2];
  const float* b1  = (const float*)d_in[3];
  const float* W2  = (const float*)d_in[4];
  const float* b2  = (const float*)d_in[5];
  const float* Wq  = (const float*)d_in[6];
  const float* bq  = (const float*)d_in[7];
  const float* Wk  = (const float*)d_in[8];
  const float* bk  = (const float*)d_in[9];
  const float* Wv  = (const float*)d_in[10];
  const float* bvw = (const float*)d_in[11];
  const float* Wo  = (const float*)d_in[12];
  const float* bo  = (const float*)d_in[13];
  const float* Wc  = (const float*)d_in[14];
  const float* bc  = (const float*)d_in[15];
  const float* W3  = (const float*)d_in[16];
  const float* b3  = (const float*)d_in[17];
  float* out = (float*)d_out;

  char* ws = (char*)d_ws;
  const size_t BIG = (size_t)MTOT * 256 * 2;       // 33.5 MB
  u16* buf0 = (u16*)(ws);                          // x1
  u16* buf1 = (u16*)(ws + BIG);                    // Q (std)
  u16* buf2 = (u16*)(ws + 2 * BIG);                // K (std)
  u16* buf3 = (u16*)(ws + 3 * BIG);                // V^T per b
  char* p = ws + 4 * BIG;
  u16* W1b = (u16*)p;              p += 128 * 256 * 2;
  u16* W2b = (u16*)p;              p += 256 * 256 * 2;
  u16* Wqb = (u16*)p;              p += 256 * 256 * 2;
  u16* Wkb = (u16*)p;              p += 256 * 256 * 2;
  u16* Wvb = (u16*)p;              p += 256 * 256 * 2;
  float* M1 = (float*)p;           p += 256 * 256 * 4;
  u16* Wz  = (u16*)p;              p += 16 * 256 * 2;
  float* bv = (float*)p;           p += 256 * 4;
  float* bz = (float*)p;           p += 16 * 4;

  dim3 blk(256);
  wconv<<<dim3(144), blk, 0, stream>>>(W1, W2, Wq, Wk, Wv, W1b, W2b, Wqb, Wkb, Wvb);
  prep1<<<dim3(256), blk, 0, stream>>>(Wc, Wo, bo, bc, M1, bv);
  prep2<<<dim3(16), blk, 0, stream>>>(W3, M1, bv, Wz, bz);

  gemm1<<<dim3(512), blk, 0, stream>>>(obs, W1b, b1, buf0);
  qkv_fused<<<dim3(1024), blk, 0, stream>>>(buf0, W2b, b2, Wqb, bq, Wkb, bk,
                                            Wvb, bvw, buf1, buf2, buf3);
  attn_fused<<<dim3(1024), blk, 0, stream>>>(buf1, buf2, buf3, adj, Wz, bz, b3, out);
}

// Round 5
// 140.497 us; speedup vs baseline: 1.1121x; 1.1121x over previous
//
#include <hip/hip_runtime.h>
#include <stdint.h>

typedef unsigned short u16;
typedef unsigned long long u64;
typedef __attribute__((ext_vector_type(8))) short short8;
typedef __attribute__((ext_vector_type(4))) float f32x4;

#define MFMA16 __builtin_amdgcn_mfma_f32_16x16x32_bf16

#define B_ 1024
#define N_ 64
#define H_ 256
#define MTOT (B_ * N_)   // 65536

__device__ __forceinline__ u16 f2bf(float f) {
  union { float f; uint32_t u; } v; v.f = f;
  uint32_t r = v.u + 0x7FFFu + ((v.u >> 16) & 1u);
  return (u16)(r >> 16);
}

union U8 { short8 v; u16 u[8]; };
union U4 { u64 v; u16 u[4]; };

__device__ __forceinline__ void cp16(const void* g, void* l) {
  __builtin_amdgcn_global_load_lds(
      (const __attribute__((address_space(1))) void*)g,
      (__attribute__((address_space(3))) void*)l, 16, 0, 0);
}

// ---------------------------------------------------------------------------
// wconv: fp32 -> bf16 for W1 (128x256) and W2,Wq,Wk (256x256). 112 blocks.
// ---------------------------------------------------------------------------
__global__ __launch_bounds__(256) void wconv(
    const float* __restrict__ W1, const float* __restrict__ W2,
    const float* __restrict__ Wq, const float* __restrict__ Wk,
    u16* o1, u16* o2, u16* oq, u16* ok) {
  int off8 = blockIdx.x * 256 + threadIdx.x;
  const float* src; u16* dst;
  if      (off8 <  4096) { src = W1; dst = o1; }
  else if (off8 < 12288) { src = W2; dst = o2; off8 -= 4096; }
  else if (off8 < 20480) { src = Wq; dst = oq; off8 -= 12288; }
  else                   { src = Wk; dst = ok; off8 -= 20480; }
  const int e = off8 * 8;
  f32x4 a = *(const f32x4*)(src + e);
  f32x4 b = *(const f32x4*)(src + e + 4);
  U8 pk;
#pragma unroll
  for (int j = 0; j < 4; j++) { pk.u[j] = f2bf(a[j]); pk.u[4 + j] = f2bf(b[j]); }
  *(short8*)(dst + e) = pk.v;
}

// ---------------------------------------------------------------------------
// prep1: M1 = Wc @ Wo (fp32), bvchain = bc + Wc @ bo
// ---------------------------------------------------------------------------
__global__ __launch_bounds__(256) void prep1(
    const float* __restrict__ Wc, const float* __restrict__ Wo,
    const float* __restrict__ bo, const float* __restrict__ bc,
    float* __restrict__ M1, float* __restrict__ bv) {
  const int j = blockIdx.x, d = threadIdx.x;
  __shared__ float wcr[256];
  __shared__ float red[4];
  wcr[d] = Wc[j * 256 + d];
  __syncthreads();
  float acc = 0.f;
  for (int i = 0; i < 256; i++) acc += wcr[i] * Wo[i * 256 + d];
  M1[j * 256 + d] = acc;
  float p = wcr[d] * bo[d];
  for (int off = 32; off >= 1; off >>= 1) p += __shfl_xor(p, off);
  if ((d & 63) == 0) red[d >> 6] = p;
  __syncthreads();
  if (d == 0) bv[j] = bc[j] + red[0] + red[1] + red[2] + red[3];
}

// ---------------------------------------------------------------------------
// prep2: Wzf = W3 @ M1 (fp32), bz = W3 @ bvchain + Wzf @ bvw  (v-bias folded)
// ---------------------------------------------------------------------------
__global__ __launch_bounds__(256) void prep2(
    const float* __restrict__ W3, const float* __restrict__ M1,
    const float* __restrict__ bvchain, const float* __restrict__ bvw,
    float* __restrict__ Wzf, float* __restrict__ bz) {
  const int a = blockIdx.x, d = threadIdx.x;
  __shared__ float w3r[256];
  __shared__ float red[4];
  w3r[d] = W3[a * 256 + d];
  __syncthreads();
  float acc = 0.f;
  for (int j = 0; j < 256; j++) acc += w3r[j] * M1[j * 256 + d];
  Wzf[a * 256 + d] = acc;
  float p = w3r[d] * bvchain[d] + acc * bvw[d];
  for (int off = 32; off >= 1; off >>= 1) p += __shfl_xor(p, off);
  if ((d & 63) == 0) red[d >> 6] = p;
  __syncthreads();
  if (d == 0) bz[a] = red[0] + red[1] + red[2] + red[3];
}

// ---------------------------------------------------------------------------
// prep3: G[h*16+a][d2] = sum_{d<64} Wzf[a][64h+d] * Wv[64h+d][d2]  -> bf16
// ---------------------------------------------------------------------------
__global__ __launch_bounds__(256) void prep3(
    const float* __restrict__ Wzf, const float* __restrict__ Wv,
    u16* __restrict__ G) {
  const int g = blockIdx.x, d2 = threadIdx.x;
  const int h = g >> 4, a = g & 15;
  __shared__ float wzr[64];
  if (d2 < 64) wzr[d2] = Wzf[a * 256 + h * 64 + d2];
  __syncthreads();
  float acc = 0.f;
#pragma unroll 8
  for (int d = 0; d < 64; d++) acc += wzr[d] * Wv[(size_t)(h * 64 + d) * 256 + d2];
  G[g * 256 + d2] = f2bf(acc);
}

// ---------------------------------------------------------------------------
// gemm1: x1 = relu(obs[M,128] @ W1^T + b1) -> bf16 std. 128x256 tile.
// ---------------------------------------------------------------------------
__global__ __launch_bounds__(256, 2) void gemm1(
    const float* __restrict__ Af, const u16* __restrict__ Wb,
    const float* __restrict__ bias, u16* __restrict__ C) {
  __shared__ char smem[49152];
  u16* As = (u16*)smem;
  u16* Bs = (u16*)(smem + 16384);
  const int tid = threadIdx.x;
  const int lane = tid & 63, wid = tid >> 6;
  const int wr = wid >> 1, wc = wid & 1;
  const int ro = lane & 15, hi = lane >> 4;
  const int m0 = blockIdx.x * 128;
  const int K = 128;

  f32x4 acc[4][8];
#pragma unroll
  for (int m = 0; m < 4; m++)
#pragma unroll
    for (int n = 0; n < 8; n++) acc[m][n] = (f32x4){0.f, 0.f, 0.f, 0.f};

  for (int k0 = 0; k0 < K; k0 += 64) {
#pragma unroll
    for (int it = 0; it < 4; it++) {
      const int e = (tid + it * 256) * 8;
      const int r = e >> 6, c = e & 63;
      const float* s = Af + (size_t)(m0 + r) * K + k0 + c;
      f32x4 a = *(const f32x4*)s, b = *(const f32x4*)(s + 4);
      U8 pk;
#pragma unroll
      for (int j = 0; j < 4; j++) { pk.u[j] = f2bf(a[j]); pk.u[4 + j] = f2bf(b[j]); }
      *(short8*)&As[r * 64 + c] = pk.v;
    }
#pragma unroll
    for (int i = 0; i < 8; i++) {
      const int boff = i * 4096 + wid * 1024;
      const int loff = boff + lane * 16;
      const int r = loff >> 7, cb = loff & 127;
      cp16(Wb + (size_t)r * K + k0 + (cb >> 1), Bs + (boff >> 1));
    }
    __syncthreads();
#pragma unroll
    for (int kk = 0; kk < 64; kk += 32) {
      short8 af[4], bfr[8];
#pragma unroll
      for (int m = 0; m < 4; m++)
        af[m] = *(const short8*)&As[(wr * 64 + m * 16 + ro) * 64 + kk + hi * 8];
#pragma unroll
      for (int n = 0; n < 8; n++)
        bfr[n] = *(const short8*)&Bs[(wc * 128 + n * 16 + ro) * 64 + kk + hi * 8];
#pragma unroll
      for (int m = 0; m < 4; m++)
#pragma unroll
        for (int n = 0; n < 8; n++)
          acc[m][n] = MFMA16(af[m], bfr[n], acc[m][n], 0, 0, 0);
    }
    __syncthreads();
  }

  u16 (*Cs)[264] = (u16(*)[264])smem;
#pragma unroll
  for (int half = 0; half < 2; half++) {
    if (wr == half) {
#pragma unroll
      for (int n = 0; n < 8; n++) {
        const int col = wc * 128 + n * 16 + ro;
        const float bb = bias[col];
#pragma unroll
        for (int m = 0; m < 4; m++)
#pragma unroll
          for (int j = 0; j < 4; j++)
            Cs[m * 16 + hi * 4 + j][col] = f2bf(fmaxf(acc[m][n][j] + bb, 0.f));
      }
    }
    __syncthreads();
    for (int i = tid; i < 64 * 32; i += 256) {
      const int r = i >> 5, c = (i & 31) << 3;
      *(short8*)(C + (size_t)(m0 + half * 64 + r) * 256 + c) = *(short8*)&Cs[r][c];
    }
    __syncthreads();
  }
}

// ---------------------------------------------------------------------------
// gemm_bt2: C = act(A[M,256] @ W[256,256]^T + b) -> bf16 std. Dual-weight:
// blockIdx.y selects (W0,b0,C0) or (W1,b1,C1) (Q and K in one launch).
// ---------------------------------------------------------------------------
template<bool RELU>
__global__ __launch_bounds__(256, 2) void gemm_bt2(
    const u16* __restrict__ A,
    const u16* __restrict__ Wa, const float* __restrict__ ba, u16* __restrict__ Ca,
    const u16* __restrict__ Wb2, const float* __restrict__ bb2, u16* __restrict__ Cb2) {
  const u16* Wb = blockIdx.y ? Wb2 : Wa;
  const float* bias = blockIdx.y ? bb2 : ba;
  u16* C = blockIdx.y ? Cb2 : Ca;
  __shared__ char smem[49152];
  u16* As = (u16*)smem;
  u16* Bs = (u16*)(smem + 16384);
  const int tid = threadIdx.x;
  const int lane = tid & 63, wid = tid >> 6;
  const int wr = wid >> 1, wc = wid & 1;
  const int ro = lane & 15, hi = lane >> 4;
  const int m0 = blockIdx.x * 128;
  const int K = 256;

  f32x4 acc[4][8];
#pragma unroll
  for (int m = 0; m < 4; m++)
#pragma unroll
    for (int n = 0; n < 8; n++) acc[m][n] = (f32x4){0.f, 0.f, 0.f, 0.f};

  for (int k0 = 0; k0 < K; k0 += 64) {
#pragma unroll
    for (int i = 0; i < 4; i++) {
      const int boff = i * 4096 + wid * 1024;
      const int loff = boff + lane * 16;
      const int r = loff >> 7, cb = loff & 127;
      cp16(A + (size_t)(m0 + r) * K + k0 + (cb >> 1), As + (boff >> 1));
    }
#pragma unroll
    for (int i = 0; i < 8; i++) {
      const int boff = i * 4096 + wid * 1024;
      const int loff = boff + lane * 16;
      const int r = loff >> 7, cb = loff & 127;
      cp16(Wb + (size_t)r * K + k0 + (cb >> 1), Bs + (boff >> 1));
    }
    __syncthreads();
#pragma unroll
    for (int kk = 0; kk < 64; kk += 32) {
      short8 af[4], bfr[8];
#pragma unroll
      for (int m = 0; m < 4; m++)
        af[m] = *(const short8*)&As[(wr * 64 + m * 16 + ro) * 64 + kk + hi * 8];
#pragma unroll
      for (int n = 0; n < 8; n++)
        bfr[n] = *(const short8*)&Bs[(wc * 128 + n * 16 + ro) * 64 + kk + hi * 8];
#pragma unroll
      for (int m = 0; m < 4; m++)
#pragma unroll
        for (int n = 0; n < 8; n++)
          acc[m][n] = MFMA16(af[m], bfr[n], acc[m][n], 0, 0, 0);
    }
    __syncthreads();
  }

  u16 (*Cs)[264] = (u16(*)[264])smem;
#pragma unroll
  for (int half = 0; half < 2; half++) {
    if (wr == half) {
#pragma unroll
      for (int n = 0; n < 8; n++) {
        const int col = wc * 128 + n * 16 + ro;
        const float bb = bias[col];
#pragma unroll
        for (int m = 0; m < 4; m++)
#pragma unroll
          for (int j = 0; j < 4; j++) {
            float val = acc[m][n][j] + bb;
            if (RELU) val = fmaxf(val, 0.f);
            Cs[m * 16 + hi * 4 + j][col] = f2bf(val);
          }
      }
    }
    __syncthreads();
    for (int i = tid; i < 64 * 32; i += 256) {
      const int r = i >> 5, c = (i & 31) << 3;
      *(short8*)(C + (size_t)(m0 + half * 64 + r) * 256 + c) = *(short8*)&Cs[r][c];
    }
    __syncthreads();
  }
}

// ---------------------------------------------------------------------------
// gemmv: Vzraw[M,64] = x2 @ G[64,256]^T, stored transposed per-b:
// Vzt[b][c=h*16+a][k=0..63] bf16 (no bias; folded into bz).
// Tile 128x64, 4 waves (wave w -> rows 32w..32w+31), acc[2][4].
// G staged once in LDS with XOR swizzle (rows stride 512B would be 16-way).
// ---------------------------------------------------------------------------
__global__ __launch_bounds__(256, 2) void gemmv(
    const u16* __restrict__ x2, const u16* __restrict__ G,
    u16* __restrict__ Vzt) {
  __shared__ char smem[49152];
  char* As = smem;                 // 128x64 bf16 = 16 KB, linear
  char* Bs = smem + 16384;         // 64x256 bf16 = 32 KB, XOR-swizzled
  const int tid = threadIdx.x;
  const int lane = tid & 63, w = tid >> 6;
  const int ro = lane & 15, hi = lane >> 4;
  const int m0 = blockIdx.x * 128;

  // stage G once: linear LDS dest, pre-swizzled global src (rule 21)
#pragma unroll
  for (int i = 0; i < 8; i++) {
    const int boff = i * 4096 + w * 1024;
    const int t = boff + lane * 16;
    const int row = t >> 9;
    const int cb = (t & 511) ^ ((row & 7) << 4);
    cp16(G + (size_t)row * 256 + (cb >> 1), Bs + boff);
  }

  f32x4 acc[2][4];
#pragma unroll
  for (int m = 0; m < 2; m++)
#pragma unroll
    for (int n = 0; n < 4; n++) acc[m][n] = (f32x4){0.f, 0.f, 0.f, 0.f};

  for (int k0 = 0; k0 < 256; k0 += 64) {
#pragma unroll
    for (int i = 0; i < 4; i++) {
      const int boff = i * 4096 + w * 1024;
      const int loff = boff + lane * 16;
      const int r = loff >> 7, cb = loff & 127;
      cp16(x2 + (size_t)(m0 + r) * 256 + k0 + (cb >> 1), As + boff);
    }
    __syncthreads();
#pragma unroll
    for (int kk = 0; kk < 64; kk += 32) {
      short8 af[2], bfr[4];
#pragma unroll
      for (int m = 0; m < 2; m++) {
        const int row = w * 32 + m * 16 + ro;
        af[m] = *(const short8*)(As + row * 128 + (kk + hi * 8) * 2);
      }
#pragma unroll
      for (int n = 0; n < 4; n++) {
        const int row = n * 16 + ro;
        bfr[n] = *(const short8*)(Bs + ((row * 512 + (k0 + kk + hi * 8) * 2) ^ ((row & 7) << 4)));
      }
#pragma unroll
      for (int m = 0; m < 2; m++)
#pragma unroll
        for (int n = 0; n < 4; n++)
          acc[m][n] = MFMA16(af[m], bfr[n], acc[m][n], 0, 0, 0);
    }
    __syncthreads();
  }

  // transposed store: Vzt[b][c][k], 4 consecutive k per u64
#pragma unroll
  for (int m = 0; m < 2; m++) {
    const int rbase = w * 32 + m * 16;
    const int bidx = (m0 >> 6) + (rbase >> 6);
    const int ke = (rbase + hi * 4) & 63;
#pragma unroll
    for (int n = 0; n < 4; n++) {
      const int c = n * 16 + ro;
      U4 pk;
#pragma unroll
      for (int j = 0; j < 4; j++) pk.u[j] = f2bf(acc[m][n][j]);
      *(u64*)(Vzt + (size_t)bidx * 4096 + (size_t)c * 64 + ke) = pk.v;
    }
  }
}

// ---------------------------------------------------------------------------
// attn_fused: per b. QK^T -> masked in-register softmax -> P@Vz (folded
// O-proj/comm weights) -> cross-head Z reduce -> out = adj@Z + b3 + deg*bz.
// ---------------------------------------------------------------------------
__global__ __launch_bounds__(256, 2) void attn_fused(
    const u16* __restrict__ Qg, const u16* __restrict__ Kg,
    const u16* __restrict__ Vzt, const float* __restrict__ adj,
    const float* __restrict__ bz, const float* __restrict__ b3,
    float* __restrict__ out) {
  __shared__ u16 Ps[4][64][72];
  __shared__ float Zs[4][64][16];
  __shared__ u64 adjm[64];
  __shared__ u16 chunk[64][4];

  const int b = blockIdx.x, tid = threadIdx.x;
  const int lane = tid & 63, w = tid >> 6;
  const int ro = lane & 15, hi = lane >> 4;
  const int hc = w * 64;
  const size_t base = (size_t)b * 64 * 256;

  short8 kb[4][2];
#pragma unroll
  for (int n = 0; n < 4; n++)
#pragma unroll
    for (int ks = 0; ks < 2; ks++)
      kb[n][ks] = *(const short8*)(Kg + base + (size_t)(n * 16 + ro) * 256 + hc + ks * 32 + hi * 8);

  {
    const int q = tid >> 2, qa = tid & 3;
    const float* ar = adj + ((size_t)b * 64 + q) * 64 + qa * 16;
    f32x4 a0 = *(const f32x4*)(ar);
    f32x4 a1 = *(const f32x4*)(ar + 4);
    f32x4 a2 = *(const f32x4*)(ar + 8);
    f32x4 a3 = *(const f32x4*)(ar + 12);
    unsigned m16 = 0;
#pragma unroll
    for (int i = 0; i < 4; i++) {
      m16 |= (unsigned)(a0[i] != 0.f) << i;
      m16 |= (unsigned)(a1[i] != 0.f) << (4 + i);
      m16 |= (unsigned)(a2[i] != 0.f) << (8 + i);
      m16 |= (unsigned)(a3[i] != 0.f) << (12 + i);
    }
    chunk[q][qa] = (u16)m16;
  }

  f32x4 s[4][4];
#pragma unroll
  for (int m = 0; m < 4; m++) {
    short8 af[2];
#pragma unroll
    for (int ks = 0; ks < 2; ks++)
      af[ks] = *(const short8*)(Qg + base + (size_t)(m * 16 + ro) * 256 + hc + ks * 32 + hi * 8);
#pragma unroll
    for (int n = 0; n < 4; n++) s[m][n] = (f32x4){0.f, 0.f, 0.f, 0.f};
#pragma unroll
    for (int ks = 0; ks < 2; ks++)
#pragma unroll
      for (int n = 0; n < 4; n++)
        s[m][n] = MFMA16(af[ks], kb[n][ks], s[m][n], 0, 0, 0);
  }

  // Vz fragments for head w (B-operand; Vzt[b][w*16+a][k])
  short8 vz[2];
#pragma unroll
  for (int ks = 0; ks < 2; ks++)
    vz[ks] = *(const short8*)(Vzt + (size_t)b * 4096 + (size_t)(hc / 4 + ro) * 64 + ks * 32 + hi * 8);

  __syncthreads();
  if (tid < 64)
    adjm[tid] = (u64)chunk[tid][0] | ((u64)chunk[tid][1] << 16) |
                ((u64)chunk[tid][2] << 32) | ((u64)chunk[tid][3] << 48);
  __syncthreads();

#pragma unroll
  for (int m = 0; m < 4; m++) {
#pragma unroll
    for (int j = 0; j < 4; j++) {
      const int q = m * 16 + hi * 4 + j;
      const u64 msk = adjm[q];
      float sv[4], ev[4];
      float mx = -3.0e38f;
#pragma unroll
      for (int n = 0; n < 4; n++) {
        const bool on = (msk >> (n * 16 + ro)) & 1ull;
        sv[n] = on ? s[m][n][j] * 0.125f : -3.0e38f;
        mx = fmaxf(mx, sv[n]);
      }
      mx = fmaxf(mx, __shfl_xor(mx, 1));
      mx = fmaxf(mx, __shfl_xor(mx, 2));
      mx = fmaxf(mx, __shfl_xor(mx, 4));
      mx = fmaxf(mx, __shfl_xor(mx, 8));
      float sum = 0.f;
#pragma unroll
      for (int n = 0; n < 4; n++) {
        ev[n] = (sv[n] > -1.0e37f) ? __expf(sv[n] - mx) : 0.f;
        sum += ev[n];
      }
      sum += __shfl_xor(sum, 1);
      sum += __shfl_xor(sum, 2);
      sum += __shfl_xor(sum, 4);
      sum += __shfl_xor(sum, 8);
      const float inv = 1.0f / sum;
#pragma unroll
      for (int n = 0; n < 4; n++)
        Ps[w][q][n * 16 + ro] = f2bf(ev[n] * inv);
    }
  }
  // own-wave DS ordering: no barrier needed before reading own Ps[w]

  // partial Z for head w: Zw = P^w @ Vz^w  (C: 64 rows x 16 cols)
#pragma unroll
  for (int m = 0; m < 4; m++) {
    short8 pa[2];
    pa[0] = *(const short8*)&Ps[w][m * 16 + ro][hi * 8];
    pa[1] = *(const short8*)&Ps[w][m * 16 + ro][32 + hi * 8];
    f32x4 oz = (f32x4){0.f, 0.f, 0.f, 0.f};
#pragma unroll
    for (int ks = 0; ks < 2; ks++)
      oz = MFMA16(pa[ks], vz[ks], oz, 0, 0, 0);
#pragma unroll
    for (int j = 0; j < 4; j++)
      Zs[w][m * 16 + hi * 4 + j][ro] = oz[j];
  }
  __syncthreads();

  // reduce heads into Zs[0]
  for (int i = tid; i < 1024; i += 256) {
    const int r = i >> 4, a = i & 15;
    Zs[0][r][a] += Zs[1][r][a] + Zs[2][r][a] + Zs[3][r][a];
  }
  __syncthreads();

  // out = adj @ Z + b3 + deg*bz
  {
    const int n = tid >> 2, a4 = (tid & 3) << 2;
    const u64 msk = adjm[n];
    const float deg = (float)__popcll(msk);
    float a0 = 0.f, a1 = 0.f, a2 = 0.f, a3 = 0.f;
#pragma unroll 8
    for (int m = 0; m < 64; m++) {
      const float wv = (float)((msk >> m) & 1ull);
      f32x4 z = *(const f32x4*)&Zs[0][m][a4];
      a0 += wv * z[0]; a1 += wv * z[1]; a2 += wv * z[2]; a3 += wv * z[3];
    }
    f32x4 r;
    r[0] = a0 + b3[a4 + 0] + deg * bz[a4 + 0];
    r[1] = a1 + b3[a4 + 1] + deg * bz[a4 + 1];
    r[2] = a2 + b3[a4 + 2] + deg * bz[a4 + 2];
    r[3] = a3 + b3[a4 + 3] + deg * bz[a4 + 3];
    *(f32x4*)(out + ((size_t)b * 64 + n) * 16 + a4) = r;
  }
}

// ---------------------------------------------------------------------------
extern "C" void kernel_launch(void* const* d_in, const int* in_sizes, int n_in,
                              void* d_out, int out_size, void* d_ws, size_t ws_size,
                              hipStream_t stream) {
  const float* obs = (const float*)d_in[0];
  const float* adj = (const float*)d_in[1];
  const float* W1  = (const float*)d_in[2];
  const float* b1  = (const float*)d_in[3];
  const float* W2  = (const float*)d_in[4];
  const float* b2  = (const float*)d_in[5];
  const float* Wq  = (const float*)d_in[6];
  const float* bq  = (const float*)d_in[7];
  const float* Wk  = (const float*)d_in[8];
  const float* bk  = (const float*)d_in[9];
  const float* Wv  = (const float*)d_in[10];
  const float* bvw = (const float*)d_in[11];
  const float* Wo  = (const float*)d_in[12];
  const float* bo  = (const float*)d_in[13];
  const float* Wc  = (const float*)d_in[14];
  const float* bc  = (const float*)d_in[15];
  const float* W3  = (const float*)d_in[16];
  const float* b3  = (const float*)d_in[17];
  float* out = (float*)d_out;

  char* ws = (char*)d_ws;
  const size_t BIG = (size_t)MTOT * 256 * 2;       // 33.5 MB
  u16* buf0 = (u16*)(ws);                          // x1, then Vzt (x1 dead)
  u16* buf1 = (u16*)(ws + BIG);                    // x2
  u16* buf2 = (u16*)(ws + 2 * BIG);                // Q
  u16* buf3 = (u16*)(ws + 3 * BIG);                // K
  char* p = ws + 4 * BIG;
  u16* W1b = (u16*)p;              p += 128 * 256 * 2;
  u16* W2b = (u16*)p;              p += 256 * 256 * 2;
  u16* Wqb = (u16*)p;              p += 256 * 256 * 2;
  u16* Wkb = (u16*)p;              p += 256 * 256 * 2;
  float* M1 = (float*)p;           p += 256 * 256 * 4;
  float* Wzf = (float*)p;          p += 16 * 256 * 4;
  u16* G   = (u16*)p;              p += 64 * 256 * 2;
  float* bv = (float*)p;           p += 256 * 4;
  float* bz = (float*)p;           p += 16 * 4;

  dim3 blk(256);
  wconv<<<dim3(112), blk, 0, stream>>>(W1, W2, Wq, Wk, W1b, W2b, Wqb, Wkb);
  prep1<<<dim3(256), blk, 0, stream>>>(Wc, Wo, bo, bc, M1, bv);
  prep2<<<dim3(16), blk, 0, stream>>>(W3, M1, bv, bvw, Wzf, bz);
  prep3<<<dim3(64), blk, 0, stream>>>(Wzf, Wv, G);

  gemm1<<<dim3(512), blk, 0, stream>>>(obs, W1b, b1, buf0);
  gemm_bt2<true ><<<dim3(512, 1), blk, 0, stream>>>(buf0, W2b, b2, buf1, W2b, b2, buf1);
  gemm_bt2<false><<<dim3(512, 2), blk, 0, stream>>>(buf1, Wqb, bq, buf2, Wkb, bk, buf3);
  gemmv<<<dim3(512), blk, 0, stream>>>(buf1, G, buf0);

  attn_fused<<<dim3(1024), blk, 0, stream>>>(buf2, buf3, buf0, adj, bz, b3, out);
}